// Round 12
// baseline (1772.282 us; speedup 1.0000x reference)
//
#include <hip/hip_runtime.h>

// Persistent cooperative LSTM decoder. NLAYERS=4, NHID=1024, NOUT=512, BSZ=64, STEPS=128.
// 256 blocks x 512 threads, 1 block/CU. Block (lyr, jt) owns 16 hidden cols of layer lyr.
// Round-12 (on r11 base, 1669us):
//  (1) amdgpu_num_vgpr(240): r6-r11 allocator stuck at 128 VGPR vs ~210-reg working set
//      -> wreg/A not resident (loop reloads from L2/IC; ~250MB/dispatch unexplained FETCH).
//      Pin to the 2-waves/SIMD budget (cap 256) so weights/acc/A stay in registers.
//  (2) depth-4 A-load pipeline (vmcnt 12/8/4/0 ladder, 16 loads in flight) - covers the
//      ~900cy IC latency that depth-2 (~300cy) could not. (r7 tested this only bundled
//      with a regressing sync; clean test here.)
// Unchanged from r11: monotonic write-once h slabs + plain cached A-loads, p2p set-once
// flags, 96KB LDS weights (K 0..767) + 5 reg chunks, transposed LDS reduce, LDS cell
// state, separate proj_kernel on the layer-3 slab.

#define H      1024
#define B      64
#define NL     4
#define BH     (B * H)
#define NOUTD  512
#define NSCAN  127
#define NWAVES 130
#define RSTR   76   // transposed reduce stride (floats)
#define KL     768  // K columns resident in LDS per gate-row

typedef __attribute__((ext_vector_type(8))) short short8;
typedef __attribute__((ext_vector_type(4))) float f32x4;

__device__ __forceinline__ unsigned short f2bf(float x) {
  union { float f; unsigned int u; } v; v.f = x;
  unsigned int r = v.u + 0x7FFFu + ((v.u >> 16) & 1u);
  return (unsigned short)(r >> 16);
}
__device__ __forceinline__ short8 pack8(float4 a, float4 b) {
  short8 r;
  r[0] = (short)f2bf(a.x); r[1] = (short)f2bf(a.y);
  r[2] = (short)f2bf(a.z); r[3] = (short)f2bf(a.w);
  r[4] = (short)f2bf(b.x); r[5] = (short)f2bf(b.y);
  r[6] = (short)f2bf(b.z); r[7] = (short)f2bf(b.w);
  return r;
}
__device__ __forceinline__ float sigmoidf_(float x) {
  return 1.0f / (1.0f + __expf(-x));
}
__device__ __forceinline__ float tanhf_(float x) {
  float ax = fabsf(x);
  float t = __expf(-2.0f * ax);
  float r = 1.0f - 2.0f * t / (1.0f + t);
  return copysignf(r, x);
}

// PLAIN cached 16B load (L1+L2). Safe: h slabs are write-once, reads are flag-gated.
__device__ __forceinline__ void ldg16(short8* d, const unsigned short* p) {
  asm volatile("global_load_dwordx4 %0, %1, off" : "=v"(*d) : "v"(p));
}
#define VMW(N) do { asm volatile("s_waitcnt vmcnt(" #N ")" ::: "memory"); \
                    __builtin_amdgcn_sched_barrier(0); } while (0)

__device__ __forceinline__ void st_h4(unsigned short* p, unsigned v) {
  __hip_atomic_store((unsigned*)p, v, __ATOMIC_RELAXED, __HIP_MEMORY_SCOPE_AGENT);
}

__global__ __launch_bounds__(512, 2)
__attribute__((amdgpu_num_vgpr(240)))
void lstm_persist(
    const float* __restrict__ hx, const float* __restrict__ cx,
    const float* __restrict__ Wm, const float* __restrict__ Um,
    unsigned short* __restrict__ hmon, unsigned* __restrict__ flags) {
  __shared__ __align__(16) unsigned short WuL[64 * KL];    // 96 KB swizzled gate weights
  __shared__ __align__(16) float red[2][64 * RSTR];        // 38.9 KB transposed reduce
  __shared__ float cS[B * 16];                             // 4 KB cell state

  const int tid = threadIdx.x;
  const int q = tid >> 6;            // wave 0..7
  const int lane = tid & 63;
  const int l15 = lane & 15;
  const int lhi = lane >> 4;
  const int bid = blockIdx.x;
  const int lyr = bid >> 6;          // 0..3
  const int jt = bid & 63;           // 16-col group

  // monotonic slab: layer l holds positions l..l+127; addr index = l*128 + (p-l)
#define HSL(l, p) (hmon + ((size_t)(l) * 128 + (size_t)((p) - (l))) * BH)
#define FROW(w) (flags + (size_t)(w) * 256)

  // ---------------- init: h -> slab position lyr + c ----------------
  {
    const int u = tid * 2;
    const int b = u >> 4, jj = u & 15;      // jj even
    const size_t gi = (size_t)lyr * BH + (size_t)b * H + jt * 16 + jj;
    const unsigned hv = (unsigned)f2bf(hx[gi]) | ((unsigned)f2bf(hx[gi + 1]) << 16);
    st_h4(HSL(lyr, lyr) + (size_t)b * H + jt * 16 + jj, hv);
    cS[b * 16 + jj] = cx[gi];
    cS[b * 16 + jj + 1] = cx[gi + 1];
  }

  // ---------------- weights: LDS part (K 0..767), swizzled ----------------
  {
    const int lr = tid >> 3;                 // local gate row 0..63
    const int kb0 = (tid & 7) * 96;          // K base (96 cols per thread)
    const int gr = (lr >> 4) * 1024 + jt * 16 + (lr & 15);
    const float* src = Um + ((size_t)lyr * 4096 + gr) * 1024 + kb0;
#pragma unroll
    for (int jc = 0; jc < 12; ++jc) {
      float4 f0 = *(const float4*)(src + jc * 8);
      float4 f1 = *(const float4*)(src + jc * 8 + 4);
      int byteoff = ((lr * KL + kb0 + jc * 8) * 2) ^ ((lr & 7) << 4);
      *(short8*)((char*)WuL + byteoff) = pack8(f0, f1);
    }
  }

  // ---------------- register weights (K >= 768): 5 chunks lyr>0, 1 chunk lyr0 ----------------
  short8 wreg[5][4];
  if (lyr == 0) {
    const int kk = KL + 32 * q + 8 * lhi;    // 768..1023
#pragma unroll
    for (int n = 0; n < 4; ++n) {
      const int gr = n * 1024 + jt * 16 + l15;
      const float* src = Um + (size_t)gr * 1024 + kk;
      wreg[0][n] = pack8(*(const float4*)src, *(const float4*)(src + 4));
    }
  } else {
#pragma unroll
    for (int c = 0; c < 5; ++c) {
      const int kk = KL + 160 * q + 32 * c + 8 * lhi;   // 768..2047
#pragma unroll
      for (int n = 0; n < 4; ++n) {
        const int gr = n * 1024 + jt * 16 + l15;
        const float* src = (kk < 1024)
            ? (Um + ((size_t)lyr * 4096 + gr) * 1024 + kk)
            : (Wm + ((size_t)(lyr - 1) * 4096 + gr) * 1024 + (kk - 1024));
        wreg[c][n] = pack8(*(const float4*)src, *(const float4*)(src + 4));
      }
    }
  }

  // ---------------- post init flag (row 0) ----------------
  asm volatile("s_waitcnt vmcnt(0)" ::: "memory");
  __syncthreads();
  if (tid == 0)
    __hip_atomic_store(FROW(0) + lyr * 64 + jt, 1u,
                       __ATOMIC_RELAXED, __HIP_MEMORY_SCOPE_AGENT);

  // ---------------- wavefront loop ----------------
  for (int w = 0; w < NWAVES; ++w) {
    const int s = w - lyr;

    if (s >= 0 && s < NSCAN) {
      // ---- dataflow wait (RAW only): 128 threads spin in parallel ----
      {
        const unsigned* row = FROW(w);
        const unsigned* myf = nullptr;
        if (tid < 64) {
          myf = row + lyr * 64 + tid;                            // own layer @ w
        } else if (tid < 128) {
          if (lyr > 0) myf = row + (lyr - 1) * 64 + (tid - 64);  // layer below @ w
        }
        if (myf)
          while (!__hip_atomic_load(myf, __ATOMIC_RELAXED, __HIP_MEMORY_SCOPE_AGENT))
            __builtin_amdgcn_s_sleep(1);
      }
      __syncthreads();

      const unsigned short* baseU = HSL(lyr, w);
      const unsigned short* baseW = (lyr > 0) ? HSL(lyr - 1, w) : HSL(lyr, w);
      const unsigned short* aU = baseU + (size_t)l15 * H + 8 * lhi;
      const unsigned short* aW = baseW + (size_t)l15 * H + 8 * lhi;

      f32x4 acc[4][4];
#pragma unroll
      for (int m = 0; m < 4; ++m)
#pragma unroll
        for (int n = 0; n < 4; ++n) acc[m][n] = (f32x4){0.f, 0.f, 0.f, 0.f};

      short8 A[4][4];   // depth-4 pipeline buffers (64 VGPR)

#define KCOL0(c)  (96 * q + 32 * (c))                         // LDS-weight chunks (c<3)
#define KCOLR(c)  (KL + 160 * q + 32 * ((c) - 3))             // reg-weight chunks lyr>0
#define KSEL(c)   ((c) < 3 ? KCOL0(c) : KCOLR(c))
#define ISSUE(buf, k) { \
    const unsigned short* _p = ((k) < 1024) ? (aU + (k)) : (aW + ((k) - 1024)); \
    ldg16(&A[buf][0], _p); \
    ldg16(&A[buf][1], _p + 16 * H); \
    ldg16(&A[buf][2], _p + 32 * H); \
    ldg16(&A[buf][3], _p + 48 * H); }

      if (lyr > 0) {
        ISSUE(0, KSEL(0)); ISSUE(1, KSEL(1)); ISSUE(2, KSEL(2)); ISSUE(3, KSEL(3));
#pragma unroll
        for (int c = 0; c < 8; ++c) {
          if (c <= 4) VMW(12); else if (c == 5) VMW(8); else if (c == 6) VMW(4); else VMW(0);
          if (c < 3) {
            const int kk = KCOL0(c);
#pragma unroll
            for (int n = 0; n < 4; ++n) {
              const int byteoff = (((n * 16 + l15) * KL + kk + 8 * lhi) * 2) ^ ((l15 & 7) << 4);
              short8 bb = *(const short8*)((const char*)WuL + byteoff);
#pragma unroll
              for (int m = 0; m < 4; ++m)
                acc[m][n] = __builtin_amdgcn_mfma_f32_16x16x32_bf16(A[c & 3][m], bb, acc[m][n], 0, 0, 0);
            }
          } else {
#pragma unroll
            for (int n = 0; n < 4; ++n)
#pragma unroll
              for (int m = 0; m < 4; ++m)
                acc[m][n] = __builtin_amdgcn_mfma_f32_16x16x32_bf16(A[c & 3][m], wreg[c - 3][n], acc[m][n], 0, 0, 0);
          }
          if (c + 4 < 8) ISSUE((c + 4) & 3, KSEL(c + 4));
        }
      } else {
        ISSUE(0, KCOL0(0)); ISSUE(1, KCOL0(1)); ISSUE(2, KCOL0(2)); ISSUE(3, KL + 32 * q);
#pragma unroll
        for (int c = 0; c < 4; ++c) {
          if (c == 0) VMW(12); else if (c == 1) VMW(8); else if (c == 2) VMW(4); else VMW(0);
          if (c < 3) {
            const int kk = KCOL0(c);
#pragma unroll
            for (int n = 0; n < 4; ++n) {
              const int byteoff = (((n * 16 + l15) * KL + kk + 8 * lhi) * 2) ^ ((l15 & 7) << 4);
              short8 bb = *(const short8*)((const char*)WuL + byteoff);
#pragma unroll
              for (int m = 0; m < 4; ++m)
                acc[m][n] = __builtin_amdgcn_mfma_f32_16x16x32_bf16(A[c & 3][m], bb, acc[m][n], 0, 0, 0);
            }
          } else {
#pragma unroll
            for (int n = 0; n < 4; ++n)
#pragma unroll
              for (int m = 0; m < 4; ++m)
                acc[m][n] = __builtin_amdgcn_mfma_f32_16x16x32_bf16(A[c & 3][m], wreg[0][n], acc[m][n], 0, 0, 0);
          }
        }
      }
#undef ISSUE
#undef KSEL
#undef KCOL0
#undef KCOLR

      // transposed vectorized reduce: 8 partials -> red[0] + red[1]
      __syncthreads();
      {
        const int rr = q >> 1;
        float* tile = red[q & 1];
        for (int r = 0; r < 4; ++r) {
          if (rr == r) {
#pragma unroll
            for (int m = 0; m < 4; ++m)
#pragma unroll
              for (int n = 0; n < 4; ++n) {
                float* p = &tile[(n * 16 + l15) * RSTR + m * 16 + lhi * 4];
                if (r == 0) *(f32x4*)p = acc[m][n];
                else { f32x4 v = *(f32x4*)p; v += acc[m][n]; *(f32x4*)p = v; }
              }
          }
          __syncthreads();
        }
      }

      // fused LSTM cell (2 adjacent hidden units per thread)
      {
        const int u = tid * 2;
        const int b = u >> 4, jj = u & 15;  // jj even
        unsigned short hyv[2];
#pragma unroll
        for (int e = 0; e < 2; ++e) {
          const int j2 = jj + e;
          const float ig = red[0][(0 * 16 + j2) * RSTR + b] + red[1][(0 * 16 + j2) * RSTR + b];
          const float fg = red[0][(1 * 16 + j2) * RSTR + b] + red[1][(1 * 16 + j2) * RSTR + b];
          const float gg = red[0][(2 * 16 + j2) * RSTR + b] + red[1][(2 * 16 + j2) * RSTR + b];
          const float og = red[0][(3 * 16 + j2) * RSTR + b] + red[1][(3 * 16 + j2) * RSTR + b];
          const float i_ = sigmoidf_(ig);
          const float f_ = sigmoidf_(fg);
          const float g_ = tanhf_(gg);
          const float o_ = sigmoidf_(og);
          const float cv = f_ * cS[b * 16 + j2] + i_ * g_;
          cS[b * 16 + j2] = cv;
          hyv[e] = f2bf(o_ * tanhf_(cv));
        }
        const unsigned packed = (unsigned)hyv[0] | ((unsigned)hyv[1] << 16);
        st_h4(HSL(lyr, w + 1) + (size_t)b * H + jt * 16 + jj, packed);
      }
    }

    // ---- drain + post flag row w+1 (every wave, active or idle) ----
    asm volatile("s_waitcnt vmcnt(0)" ::: "memory");
    __syncthreads();
    if (tid == 0)
      __hip_atomic_store(FROW(w + 1) + lyr * 64 + jt, 1u,
                         __ATOMIC_RELAXED, __HIP_MEMORY_SCOPE_AGENT);
  }
#undef HSL
#undef FROW
}

// ---------------- batched output projection: out[t] = h3[t] @ L^T ----------------
// h3 history = layer-3 monotonic slab (position t+3 = slab index t). M = 8192, N = 512, K = 1024.
__global__ __launch_bounds__(256) void proj_kernel(
    const unsigned short* __restrict__ hist, const float* __restrict__ Lm,
    float* __restrict__ out) {
  __shared__ __align__(16) unsigned short As[64 * 136];
  const int tid = threadIdx.x;
  const int q = tid >> 6;
  const int lane = tid & 63;
  const int l15 = lane & 15;
  const int lhi = lane >> 4;
  const int mt = blockIdx.x >> 3;
  const int nt = blockIdx.x & 7;

  f32x4 acc[4];
#pragma unroll
  for (int m = 0; m < 4; ++m) acc[m] = (f32x4){0.f, 0.f, 0.f, 0.f};

  for (int kb = 0; kb < 8; ++kb) {
    __syncthreads();
#pragma unroll
    for (int i = 0; i < 4; ++i) {
      int g = tid + 256 * i;
      int row = g >> 4, cu = g & 15;
      *(short8*)(&As[row * 136 + cu * 8]) =
          *(const short8*)(&hist[((size_t)mt * 64 + row) * H + kb * 128 + cu * 8]);
    }
    __syncthreads();
#pragma unroll
    for (int kk = 0; kk < 4; ++kk) {
      const int ko = kk * 32 + 8 * lhi;
      const float* src = Lm + ((size_t)nt * 64 + q * 16 + l15) * H + kb * 128 + ko;
      short8 bb = pack8(*(const float4*)src, *(const float4*)(src + 4));
#pragma unroll
      for (int m = 0; m < 4; ++m) {
        short8 a = *(const short8*)(&As[(m * 16 + l15) * 136 + ko]);
        acc[m] = __builtin_amdgcn_mfma_f32_16x16x32_bf16(a, bb, acc[m], 0, 0, 0);
      }
    }
  }
  const int col = nt * 64 + q * 16 + l15;
#pragma unroll
  for (int m = 0; m < 4; ++m)
#pragma unroll
    for (int j = 0; j < 4; ++j) {
      const int row = mt * 64 + m * 16 + lhi * 4 + j;
      out[(size_t)row * NOUTD + col] = acc[m][j];
    }
}

extern "C" void kernel_launch(void* const* d_in, const int* in_sizes, int n_in,
                              void* d_out, int out_size, void* d_ws, size_t ws_size,
                              hipStream_t stream) {
  const float* hx = (const float*)d_in[0];
  const float* cx = (const float*)d_in[1];
  const float* Wm = (const float*)d_in[2];
  const float* Um = (const float*)d_in[3];
  const float* Lm = (const float*)d_in[4];
  float* out = (float*)d_out;

  char* ws = (char*)d_ws;
  unsigned* flags = (unsigned*)ws;                              // 256 KB flag rows
  unsigned short* hmon = (unsigned short*)(ws + (1 << 18));     // 64 MiB monotonic h slabs

  hipMemsetAsync(flags, 0, 262144, stream);

  void* args[] = {(void*)&hx, (void*)&cx, (void*)&Wm, (void*)&Um,
                  (void*)&hmon, (void*)&flags};
  hipLaunchCooperativeKernel((const void*)lstm_persist, dim3(256), dim3(512),
                             args, 0, stream);
  // layer-3 slab base: position t+3 lives at slab index t  => history rows = t*BH
  const unsigned short* hist = hmon + (size_t)3 * 128 * BH;
  proj_kernel<<<dim3(1024), dim3(256), 0, stream>>>(hist, Lm, out);
}

// Round 13
// 1328.378 us; speedup vs baseline: 1.3342x; 1.3342x over previous
//
#include <hip/hip_runtime.h>

// Persistent cooperative LSTM decoder. NLAYERS=4, NHID=1024, NOUT=512, BSZ=64, STEPS=128.
// 256 blocks x 512 threads, 1 block/CU. Block (lyr, jt) owns 16 hidden cols of layer lyr.
// Round-13 (on r11 base, 1669us): TILED h LAYOUT for contiguous A-loads.
//  - h[l][w] stored as 32 k-tiles of [64 rows][32 cols] bf16 (4KB each, row stride 64B)
//    instead of row-major [64][1024]. One A-load instruction (16B/lane x 64 lanes) now
//    covers a CONTIGUOUS 1KB (16 adjacent rows x 64B): 8 fully-used 128B lines vs
//    r11's 16 half-used lines. Halves the L2 request count of the dominant ~7us
//    A-read term (per-CU miss-concurrency x latency bound).
//  - producer (cell/init) writes tiled addresses; proj_kernel reads tiled.
// Reverted from r12: depth-4 ladder and amdgpu_num_vgpr (both null/regressive).
// Unchanged from r11: monotonic write-once slabs, plain cached A-loads, p2p set-once
// flags, 96KB LDS weights + 5 reg chunks, transposed LDS reduce, LDS cell state.

#define H      1024
#define B      64
#define NL     4
#define BH     (B * H)
#define NOUTD  512
#define NSCAN  127
#define NWAVES 130
#define RSTR   76   // transposed reduce stride (floats)
#define KL     768  // K columns resident in LDS per gate-row

typedef __attribute__((ext_vector_type(8))) short short8;
typedef __attribute__((ext_vector_type(4))) float f32x4;

__device__ __forceinline__ unsigned short f2bf(float x) {
  union { float f; unsigned int u; } v; v.f = x;
  unsigned int r = v.u + 0x7FFFu + ((v.u >> 16) & 1u);
  return (unsigned short)(r >> 16);
}
__device__ __forceinline__ short8 pack8(float4 a, float4 b) {
  short8 r;
  r[0] = (short)f2bf(a.x); r[1] = (short)f2bf(a.y);
  r[2] = (short)f2bf(a.z); r[3] = (short)f2bf(a.w);
  r[4] = (short)f2bf(b.x); r[5] = (short)f2bf(b.y);
  r[6] = (short)f2bf(b.z); r[7] = (short)f2bf(b.w);
  return r;
}
__device__ __forceinline__ float sigmoidf_(float x) {
  return 1.0f / (1.0f + __expf(-x));
}
__device__ __forceinline__ float tanhf_(float x) {
  float ax = fabsf(x);
  float t = __expf(-2.0f * ax);
  float r = 1.0f - 2.0f * t / (1.0f + t);
  return copysignf(r, x);
}

// PLAIN cached 16B load (L1+L2). Safe: h slabs are write-once, reads are flag-gated.
__device__ __forceinline__ void ldg16(short8* d, const unsigned short* p) {
  asm volatile("global_load_dwordx4 %0, %1, off" : "=v"(*d) : "v"(p));
}
#define VMWAIT4 do { asm volatile("s_waitcnt vmcnt(4)" ::: "memory"); \
                     __builtin_amdgcn_sched_barrier(0); } while (0)
#define VMWAIT0 do { asm volatile("s_waitcnt vmcnt(0)" ::: "memory"); \
                     __builtin_amdgcn_sched_barrier(0); } while (0)

__device__ __forceinline__ void st_h4(unsigned short* p, unsigned v) {
  __hip_atomic_store((unsigned*)p, v, __ATOMIC_RELAXED, __HIP_MEMORY_SCOPE_AGENT);
}

__global__ __launch_bounds__(512, 2)
__attribute__((amdgpu_waves_per_eu(2, 2)))
void lstm_persist(
    const float* __restrict__ hx, const float* __restrict__ cx,
    const float* __restrict__ Wm, const float* __restrict__ Um,
    unsigned short* __restrict__ hmon, unsigned* __restrict__ flags) {
  __shared__ __align__(16) unsigned short WuL[64 * KL];    // 96 KB swizzled gate weights
  __shared__ __align__(16) float red[2][64 * RSTR];        // 38.9 KB transposed reduce
  __shared__ float cS[B * 16];                             // 4 KB cell state

  const int tid = threadIdx.x;
  const int q = tid >> 6;            // wave 0..7
  const int lane = tid & 63;
  const int l15 = lane & 15;
  const int lhi = lane >> 4;
  const int bid = blockIdx.x;
  const int lyr = bid >> 6;          // 0..3
  const int jt = bid & 63;           // 16-col group

  // monotonic slab: layer l holds positions l..l+127; 128KB each, TILED layout:
  // element (b, col) lives at (col>>5)*2048 + b*32 + (col&31)   [32 tiles of [64][32]]
#define HSL(l, p) (hmon + ((size_t)(l) * 128 + (size_t)((p) - (l))) * BH)
#define TOFF(b, col) (((size_t)((col) >> 5)) * 2048 + (size_t)(b) * 32 + ((col) & 31))
#define FROW(w) (flags + (size_t)(w) * 256)

  // ---------------- init: h -> slab position lyr (tiled) + c ----------------
  {
    const int u = tid * 2;
    const int b = u >> 4, jj = u & 15;      // jj even
    const int C = jt * 16 + jj;             // global col, even
    const size_t gi = (size_t)lyr * BH + (size_t)b * H + C;
    const unsigned hv = (unsigned)f2bf(hx[gi]) | ((unsigned)f2bf(hx[gi + 1]) << 16);
    st_h4(HSL(lyr, lyr) + TOFF(b, C), hv);
    cS[b * 16 + jj] = cx[gi];
    cS[b * 16 + jj + 1] = cx[gi + 1];
  }

  // ---------------- weights: LDS part (K 0..767), swizzled ----------------
  {
    const int lr = tid >> 3;                 // local gate row 0..63
    const int kb0 = (tid & 7) * 96;          // K base (96 cols per thread)
    const int gr = (lr >> 4) * 1024 + jt * 16 + (lr & 15);
    const float* src = Um + ((size_t)lyr * 4096 + gr) * 1024 + kb0;
#pragma unroll
    for (int jc = 0; jc < 12; ++jc) {
      float4 f0 = *(const float4*)(src + jc * 8);
      float4 f1 = *(const float4*)(src + jc * 8 + 4);
      int byteoff = ((lr * KL + kb0 + jc * 8) * 2) ^ ((lr & 7) << 4);
      *(short8*)((char*)WuL + byteoff) = pack8(f0, f1);
    }
  }

  // ---------------- register weights (K >= 768): 5 chunks lyr>0, 1 chunk lyr0 ----------------
  short8 wreg[5][4];
  if (lyr == 0) {
    const int kk = KL + 32 * q + 8 * lhi;    // 768..1023
#pragma unroll
    for (int n = 0; n < 4; ++n) {
      const int gr = n * 1024 + jt * 16 + l15;
      const float* src = Um + (size_t)gr * 1024 + kk;
      wreg[0][n] = pack8(*(const float4*)src, *(const float4*)(src + 4));
    }
  } else {
#pragma unroll
    for (int c = 0; c < 5; ++c) {
      const int kk = KL + 160 * q + 32 * c + 8 * lhi;   // 768..2047
#pragma unroll
      for (int n = 0; n < 4; ++n) {
        const int gr = n * 1024 + jt * 16 + l15;
        const float* src = (kk < 1024)
            ? (Um + ((size_t)lyr * 4096 + gr) * 1024 + kk)
            : (Wm + ((size_t)(lyr - 1) * 4096 + gr) * 1024 + (kk - 1024));
        wreg[c][n] = pack8(*(const float4*)src, *(const float4*)(src + 4));
      }
    }
  }

  // ---------------- post init flag (row 0) ----------------
  asm volatile("s_waitcnt vmcnt(0)" ::: "memory");
  __syncthreads();
  if (tid == 0)
    __hip_atomic_store(FROW(0) + lyr * 64 + jt, 1u,
                       __ATOMIC_RELAXED, __HIP_MEMORY_SCOPE_AGENT);

  // ---------------- wavefront loop ----------------
  for (int w = 0; w < NWAVES; ++w) {
    const int s = w - lyr;

    if (s >= 0 && s < NSCAN) {
      // ---- dataflow wait (RAW only): 128 threads spin in parallel ----
      {
        const unsigned* row = FROW(w);
        const unsigned* myf = nullptr;
        if (tid < 64) {
          myf = row + lyr * 64 + tid;                            // own layer @ w
        } else if (tid < 128) {
          if (lyr > 0) myf = row + (lyr - 1) * 64 + (tid - 64);  // layer below @ w
        }
        if (myf)
          while (!__hip_atomic_load(myf, __ATOMIC_RELAXED, __HIP_MEMORY_SCOPE_AGENT))
            __builtin_amdgcn_s_sleep(1);
      }
      __syncthreads();

      // per-lane A base inside a tile: row l15, col-group lhi (16B)
      const unsigned short* aU = HSL(lyr, w) + (size_t)l15 * 32 + lhi * 8;
      const unsigned short* aW = ((lyr > 0) ? HSL(lyr - 1, w) : HSL(lyr, w))
                                 + (size_t)l15 * 32 + lhi * 8;

      f32x4 acc[4][4];
#pragma unroll
      for (int m = 0; m < 4; ++m)
#pragma unroll
        for (int n = 0; n < 4; ++n) acc[m][n] = (f32x4){0.f, 0.f, 0.f, 0.f};

      short8 A[2][4];

#define KCOL0(c)  (96 * q + 32 * (c))                         // LDS-weight chunks (c<3)
#define KCOLR(c)  (KL + 160 * q + 32 * ((c) - 3))             // reg-weight chunks lyr>0
      // tiled ISSUE: tile = k>>5 (4KB), A[m] at +m*512 elems (16 rows); each load
      // instruction covers a contiguous 1KB across the 64 lanes.
#define ISSUE(buf, k) { \
    const unsigned short* _p = ((k) < 1024) ? (aU + (size_t)((k) >> 5) * 2048) \
                                            : (aW + (size_t)(((k) - 1024) >> 5) * 2048); \
    ldg16(&A[buf][0], _p); \
    ldg16(&A[buf][1], _p + 512); \
    ldg16(&A[buf][2], _p + 1024); \
    ldg16(&A[buf][3], _p + 1536); }

      if (lyr > 0) {
        ISSUE(0, KCOL0(0));
        ISSUE(1, KCOL0(1));
#pragma unroll
        for (int c = 0; c < 8; ++c) {
          if (c < 7) VMWAIT4; else VMWAIT0;
          if (c < 3) {
            const int kk = KCOL0(c);
#pragma unroll
            for (int n = 0; n < 4; ++n) {
              const int byteoff = (((n * 16 + l15) * KL + kk + 8 * lhi) * 2) ^ ((l15 & 7) << 4);
              short8 bb = *(const short8*)((const char*)WuL + byteoff);
#pragma unroll
              for (int m = 0; m < 4; ++m)
                acc[m][n] = __builtin_amdgcn_mfma_f32_16x16x32_bf16(A[c & 1][m], bb, acc[m][n], 0, 0, 0);
            }
          } else {
#pragma unroll
            for (int n = 0; n < 4; ++n)
#pragma unroll
              for (int m = 0; m < 4; ++m)
                acc[m][n] = __builtin_amdgcn_mfma_f32_16x16x32_bf16(A[c & 1][m], wreg[c - 3][n], acc[m][n], 0, 0, 0);
          }
          if (c + 2 < 8) {
            const int k2 = (c + 2 < 3) ? KCOL0(c + 2) : KCOLR(c + 2);
            ISSUE(c & 1, k2);
          }
        }
      } else {
        ISSUE(0, KCOL0(0));
        ISSUE(1, KCOL0(1));
#pragma unroll
        for (int c = 0; c < 4; ++c) {
          if (c < 3) VMWAIT4; else VMWAIT0;
          if (c < 3) {
            const int kk = KCOL0(c);
#pragma unroll
            for (int n = 0; n < 4; ++n) {
              const int byteoff = (((n * 16 + l15) * KL + kk + 8 * lhi) * 2) ^ ((l15 & 7) << 4);
              short8 bb = *(const short8*)((const char*)WuL + byteoff);
#pragma unroll
              for (int m = 0; m < 4; ++m)
                acc[m][n] = __builtin_amdgcn_mfma_f32_16x16x32_bf16(A[c & 1][m], bb, acc[m][n], 0, 0, 0);
            }
          } else {
#pragma unroll
            for (int n = 0; n < 4; ++n)
#pragma unroll
              for (int m = 0; m < 4; ++m)
                acc[m][n] = __builtin_amdgcn_mfma_f32_16x16x32_bf16(A[c & 1][m], wreg[0][n], acc[m][n], 0, 0, 0);
          }
          if (c + 2 < 4) ISSUE(c & 1, KCOL0(c + 2));
        }
      }
#undef ISSUE
#undef KCOL0
#undef KCOLR

      // transposed vectorized reduce: 8 partials -> red[0] + red[1]
      __syncthreads();
      {
        const int rr = q >> 1;
        float* tile = red[q & 1];
        for (int r = 0; r < 4; ++r) {
          if (rr == r) {
#pragma unroll
            for (int m = 0; m < 4; ++m)
#pragma unroll
              for (int n = 0; n < 4; ++n) {
                float* p = &tile[(n * 16 + l15) * RSTR + m * 16 + lhi * 4];
                if (r == 0) *(f32x4*)p = acc[m][n];
                else { f32x4 v = *(f32x4*)p; v += acc[m][n]; *(f32x4*)p = v; }
              }
          }
          __syncthreads();
        }
      }

      // fused LSTM cell (2 adjacent hidden units per thread)
      {
        const int u = tid * 2;
        const int b = u >> 4, jj = u & 15;  // jj even
        const int C = jt * 16 + jj;         // global col, even
        unsigned short hyv[2];
#pragma unroll
        for (int e = 0; e < 2; ++e) {
          const int j2 = jj + e;
          const float ig = red[0][(0 * 16 + j2) * RSTR + b] + red[1][(0 * 16 + j2) * RSTR + b];
          const float fg = red[0][(1 * 16 + j2) * RSTR + b] + red[1][(1 * 16 + j2) * RSTR + b];
          const float gg = red[0][(2 * 16 + j2) * RSTR + b] + red[1][(2 * 16 + j2) * RSTR + b];
          const float og = red[0][(3 * 16 + j2) * RSTR + b] + red[1][(3 * 16 + j2) * RSTR + b];
          const float i_ = sigmoidf_(ig);
          const float f_ = sigmoidf_(fg);
          const float g_ = tanhf_(gg);
          const float o_ = sigmoidf_(og);
          const float cv = f_ * cS[b * 16 + j2] + i_ * g_;
          cS[b * 16 + j2] = cv;
          hyv[e] = f2bf(o_ * tanhf_(cv));
        }
        const unsigned packed = (unsigned)hyv[0] | ((unsigned)hyv[1] << 16);
        st_h4(HSL(lyr, w + 1) + TOFF(b, C), packed);
      }
    }

    // ---- drain + post flag row w+1 (every wave, active or idle) ----
    asm volatile("s_waitcnt vmcnt(0)" ::: "memory");
    __syncthreads();
    if (tid == 0)
      __hip_atomic_store(FROW(w + 1) + lyr * 64 + jt, 1u,
                         __ATOMIC_RELAXED, __HIP_MEMORY_SCOPE_AGENT);
  }
#undef HSL
#undef TOFF
#undef FROW
}

// ---------------- batched output projection: out[t] = h3[t] @ L^T ----------------
// h3 history = layer-3 monotonic slab (TILED layout), position t at slab index t.
// M = 8192 (= 128 positions x 64 rows), N = 512, K = 1024. mt = position index.
__global__ __launch_bounds__(256) void proj_kernel(
    const unsigned short* __restrict__ hist, const float* __restrict__ Lm,
    float* __restrict__ out) {
  __shared__ __align__(16) unsigned short As[64 * 136];
  const int tid = threadIdx.x;
  const int q = tid >> 6;
  const int lane = tid & 63;
  const int l15 = lane & 15;
  const int lhi = lane >> 4;
  const int mt = blockIdx.x >> 3;   // position (time) index 0..127
  const int nt = blockIdx.x & 7;

  f32x4 acc[4];
#pragma unroll
  for (int m = 0; m < 4; ++m) acc[m] = (f32x4){0.f, 0.f, 0.f, 0.f};

  for (int kb = 0; kb < 8; ++kb) {
    __syncthreads();
#pragma unroll
    for (int i = 0; i < 4; ++i) {
      int g = tid + 256 * i;
      int row = g >> 4, cu = g & 15;
      const int C = kb * 128 + cu * 8;   // global k-col of the 8-elem chunk
      *(short8*)(&As[row * 136 + cu * 8]) =
          *(const short8*)(&hist[(size_t)mt * 65536 + (size_t)(C >> 5) * 2048
                                 + (size_t)row * 32 + (C & 31)]);
    }
    __syncthreads();
#pragma unroll
    for (int kk = 0; kk < 4; ++kk) {
      const int ko = kk * 32 + 8 * lhi;
      const float* src = Lm + ((size_t)nt * 64 + q * 16 + l15) * H + kb * 128 + ko;
      short8 bb = pack8(*(const float4*)src, *(const float4*)(src + 4));
#pragma unroll
      for (int m = 0; m < 4; ++m) {
        short8 a = *(const short8*)(&As[(m * 16 + l15) * 136 + ko]);
        acc[m] = __builtin_amdgcn_mfma_f32_16x16x32_bf16(a, bb, acc[m], 0, 0, 0);
      }
    }
  }
  const int col = nt * 64 + q * 16 + l15;
#pragma unroll
  for (int m = 0; m < 4; ++m)
#pragma unroll
    for (int j = 0; j < 4; ++j) {
      const int row = mt * 64 + m * 16 + lhi * 4 + j;
      out[(size_t)row * NOUTD + col] = acc[m][j];
    }
}

extern "C" void kernel_launch(void* const* d_in, const int* in_sizes, int n_in,
                              void* d_out, int out_size, void* d_ws, size_t ws_size,
                              hipStream_t stream) {
  const float* hx = (const float*)d_in[0];
  const float* cx = (const float*)d_in[1];
  const float* Wm = (const float*)d_in[2];
  const float* Um = (const float*)d_in[3];
  const float* Lm = (const float*)d_in[4];
  float* out = (float*)d_out;

  char* ws = (char*)d_ws;
  unsigned* flags = (unsigned*)ws;                              // 256 KB flag rows
  unsigned short* hmon = (unsigned short*)(ws + (1 << 18));     // 64 MiB monotonic h slabs

  hipMemsetAsync(flags, 0, 262144, stream);

  void* args[] = {(void*)&hx, (void*)&cx, (void*)&Wm, (void*)&Um,
                  (void*)&hmon, (void*)&flags};
  hipLaunchCooperativeKernel((const void*)lstm_persist, dim3(256), dim3(512),
                             args, 0, stream);
  // layer-3 slab base: position t+3 lives at slab index t => history row-block t
  const unsigned short* hist = hmon + (size_t)3 * 128 * BH;
  proj_kernel<<<dim3(1024), dim3(256), 0, stream>>>(hist, Lm, out);
}

// Round 14
// 1270.036 us; speedup vs baseline: 1.3955x; 1.0459x over previous
//
#include <hip/hip_runtime.h>

// Persistent cooperative LSTM decoder. NLAYERS=4, NHID=1024, NOUT=512, BSZ=64, STEPS=128.
// 256 blocks x 512 threads, 1 block/CU. Block (lyr, jt) owns 16 hidden cols of layer lyr.
// Round-14 (on r13 base, 1328us): SHORTEN THE PER-HOP TAIL.
//  - KL 768->512 (LDS weights 96->64KB) frees room for FOUR reduce tiles [64][68] f32
//    -> reduce is 2 rounds (waves 0-3 write, waves 4-7 add) instead of 4; and the
//    pre-reduce syncthreads is dropped (prev wave's end-sync already separates).
//    Barriers per wave: 7 -> 4. Stride 68 floats = 2-way LDS banks (free, m136).
//  - reg weights grow to 6 chunks/wave (96 VGPR), kk = 512+192q+32c.
// Unchanged from r13: tiled write-once h slabs + plain cached contiguous A-loads,
// p2p set-once flags, depth-2 vmcnt ladder, LDS cell state, proj_kernel on slab 3.

#define H      1024
#define B      64
#define NL     4
#define BH     (B * H)
#define NOUTD  512
#define NSCAN  127
#define NWAVES 130
#define RSTR   68   // reduce tile stride (floats): 16B-aligned rows, 2-way banks
#define KL     512  // K columns resident in LDS per gate-row

typedef __attribute__((ext_vector_type(8))) short short8;
typedef __attribute__((ext_vector_type(4))) float f32x4;

__device__ __forceinline__ unsigned short f2bf(float x) {
  union { float f; unsigned int u; } v; v.f = x;
  unsigned int r = v.u + 0x7FFFu + ((v.u >> 16) & 1u);
  return (unsigned short)(r >> 16);
}
__device__ __forceinline__ short8 pack8(float4 a, float4 b) {
  short8 r;
  r[0] = (short)f2bf(a.x); r[1] = (short)f2bf(a.y);
  r[2] = (short)f2bf(a.z); r[3] = (short)f2bf(a.w);
  r[4] = (short)f2bf(b.x); r[5] = (short)f2bf(b.y);
  r[6] = (short)f2bf(b.z); r[7] = (short)f2bf(b.w);
  return r;
}
__device__ __forceinline__ float sigmoidf_(float x) {
  return 1.0f / (1.0f + __expf(-x));
}
__device__ __forceinline__ float tanhf_(float x) {
  float ax = fabsf(x);
  float t = __expf(-2.0f * ax);
  float r = 1.0f - 2.0f * t / (1.0f + t);
  return copysignf(r, x);
}

// PLAIN cached 16B load (L1+L2). Safe: h slabs are write-once, reads are flag-gated.
__device__ __forceinline__ void ldg16(short8* d, const unsigned short* p) {
  asm volatile("global_load_dwordx4 %0, %1, off" : "=v"(*d) : "v"(p));
}
#define VMWAIT4 do { asm volatile("s_waitcnt vmcnt(4)" ::: "memory"); \
                     __builtin_amdgcn_sched_barrier(0); } while (0)
#define VMWAIT0 do { asm volatile("s_waitcnt vmcnt(0)" ::: "memory"); \
                     __builtin_amdgcn_sched_barrier(0); } while (0)

__device__ __forceinline__ void st_h4(unsigned short* p, unsigned v) {
  __hip_atomic_store((unsigned*)p, v, __ATOMIC_RELAXED, __HIP_MEMORY_SCOPE_AGENT);
}

__global__ __launch_bounds__(512, 2)
__attribute__((amdgpu_waves_per_eu(2, 2)))
void lstm_persist(
    const float* __restrict__ hx, const float* __restrict__ cx,
    const float* __restrict__ Wm, const float* __restrict__ Um,
    unsigned short* __restrict__ hmon, unsigned* __restrict__ flags) {
  __shared__ __align__(16) unsigned short WuL[64 * KL];    // 64 KB swizzled gate weights
  __shared__ __align__(16) float red[4][64 * RSTR];        // 68 KB: 4 reduce tiles
  __shared__ float cS[B * 16];                             // 4 KB cell state

  const int tid = threadIdx.x;
  const int q = tid >> 6;            // wave 0..7
  const int lane = tid & 63;
  const int l15 = lane & 15;
  const int lhi = lane >> 4;
  const int bid = blockIdx.x;
  const int lyr = bid >> 6;          // 0..3
  const int jt = bid & 63;           // 16-col group

  // monotonic slab: layer l holds positions l..l+127; 128KB each, TILED layout:
  // element (b, col) lives at (col>>5)*2048 + b*32 + (col&31)   [32 tiles of [64][32]]
#define HSL(l, p) (hmon + ((size_t)(l) * 128 + (size_t)((p) - (l))) * BH)
#define TOFF(b, col) (((size_t)((col) >> 5)) * 2048 + (size_t)(b) * 32 + ((col) & 31))
#define FROW(w) (flags + (size_t)(w) * 256)

  // ---------------- init: h -> slab position lyr (tiled) + c ----------------
  {
    const int u = tid * 2;
    const int b = u >> 4, jj = u & 15;      // jj even
    const int C = jt * 16 + jj;             // global col, even
    const size_t gi = (size_t)lyr * BH + (size_t)b * H + C;
    const unsigned hv = (unsigned)f2bf(hx[gi]) | ((unsigned)f2bf(hx[gi + 1]) << 16);
    st_h4(HSL(lyr, lyr) + TOFF(b, C), hv);
    cS[b * 16 + jj] = cx[gi];
    cS[b * 16 + jj + 1] = cx[gi + 1];
  }

  // ---------------- weights: LDS part (K 0..511), swizzled ----------------
  {
    const int lr = tid >> 3;                 // local gate row 0..63
    const int kb0 = (tid & 7) * 64;          // K base (64 cols per thread)
    const int gr = (lr >> 4) * 1024 + jt * 16 + (lr & 15);
    const float* src = Um + ((size_t)lyr * 4096 + gr) * 1024 + kb0;
#pragma unroll
    for (int jc = 0; jc < 8; ++jc) {
      float4 f0 = *(const float4*)(src + jc * 8);
      float4 f1 = *(const float4*)(src + jc * 8 + 4);
      int byteoff = ((lr * KL + kb0 + jc * 8) * 2) ^ ((lr & 7) << 4);
      *(short8*)((char*)WuL + byteoff) = pack8(f0, f1);
    }
  }

  // ---------------- register weights (K >= 512): 6 chunks lyr>0, 2 chunks lyr0 ----------------
  short8 wreg[6][4];
  if (lyr == 0) {
#pragma unroll
    for (int c = 0; c < 2; ++c) {
      const int kk = KL + 64 * q + 32 * c + 8 * lhi;    // 512..1023
#pragma unroll
      for (int n = 0; n < 4; ++n) {
        const int gr = n * 1024 + jt * 16 + l15;
        const float* src = Um + (size_t)gr * 1024 + kk;
        wreg[c][n] = pack8(*(const float4*)src, *(const float4*)(src + 4));
      }
    }
  } else {
#pragma unroll
    for (int c = 0; c < 6; ++c) {
      const int kk = KL + 192 * q + 32 * c + 8 * lhi;   // 512..2047
#pragma unroll
      for (int n = 0; n < 4; ++n) {
        const int gr = n * 1024 + jt * 16 + l15;
        const float* src = (kk < 1024)
            ? (Um + ((size_t)lyr * 4096 + gr) * 1024 + kk)
            : (Wm + ((size_t)(lyr - 1) * 4096 + gr) * 1024 + (kk - 1024));
        wreg[c][n] = pack8(*(const float4*)src, *(const float4*)(src + 4));
      }
    }
  }

  // ---------------- post init flag (row 0) ----------------
  asm volatile("s_waitcnt vmcnt(0)" ::: "memory");
  __syncthreads();
  if (tid == 0)
    __hip_atomic_store(FROW(0) + lyr * 64 + jt, 1u,
                       __ATOMIC_RELAXED, __HIP_MEMORY_SCOPE_AGENT);

  // ---------------- wavefront loop ----------------
  for (int w = 0; w < NWAVES; ++w) {
    const int s = w - lyr;

    if (s >= 0 && s < NSCAN) {
      // ---- dataflow wait (RAW only): 128 threads spin in parallel ----
      {
        const unsigned* row = FROW(w);
        const unsigned* myf = nullptr;
        if (tid < 64) {
          myf = row + lyr * 64 + tid;                            // own layer @ w
        } else if (tid < 128) {
          if (lyr > 0) myf = row + (lyr - 1) * 64 + (tid - 64);  // layer below @ w
        }
        if (myf)
          while (!__hip_atomic_load(myf, __ATOMIC_RELAXED, __HIP_MEMORY_SCOPE_AGENT))
            __builtin_amdgcn_s_sleep(1);
      }
      __syncthreads();

      // per-lane A base inside a tile: row l15, col-group lhi (16B)
      const unsigned short* aU = HSL(lyr, w) + (size_t)l15 * 32 + lhi * 8;
      const unsigned short* aW = ((lyr > 0) ? HSL(lyr - 1, w) : HSL(lyr, w))
                                 + (size_t)l15 * 32 + lhi * 8;

      f32x4 acc[4][4];
#pragma unroll
      for (int m = 0; m < 4; ++m)
#pragma unroll
        for (int n = 0; n < 4; ++n) acc[m][n] = (f32x4){0.f, 0.f, 0.f, 0.f};

      short8 A[2][4];

      // chunk c: c<2 -> LDS weights at kk = 64q+32c; c>=2 -> wreg[c-2]
#define KSEL1(c)  ((c) < 2 ? (64 * q + 32 * (c)) : (KL + 192 * q + 32 * ((c) - 2)))
#define KSEL0(c)  ((c) < 2 ? (64 * q + 32 * (c)) : (KL + 64 * q + 32 * ((c) - 2)))
#define ISSUE(buf, k) { \
    const unsigned short* _p = ((k) < 1024) ? (aU + (size_t)((k) >> 5) * 2048) \
                                            : (aW + (size_t)(((k) - 1024) >> 5) * 2048); \
    ldg16(&A[buf][0], _p); \
    ldg16(&A[buf][1], _p + 512); \
    ldg16(&A[buf][2], _p + 1024); \
    ldg16(&A[buf][3], _p + 1536); }

      if (lyr > 0) {
        ISSUE(0, KSEL1(0));
        ISSUE(1, KSEL1(1));
#pragma unroll
        for (int c = 0; c < 8; ++c) {
          if (c < 7) VMWAIT4; else VMWAIT0;
          if (c < 2) {
            const int kk = 64 * q + 32 * c;
#pragma unroll
            for (int n = 0; n < 4; ++n) {
              const int byteoff = (((n * 16 + l15) * KL + kk + 8 * lhi) * 2) ^ ((l15 & 7) << 4);
              short8 bb = *(const short8*)((const char*)WuL + byteoff);
#pragma unroll
              for (int m = 0; m < 4; ++m)
                acc[m][n] = __builtin_amdgcn_mfma_f32_16x16x32_bf16(A[c & 1][m], bb, acc[m][n], 0, 0, 0);
            }
          } else {
#pragma unroll
            for (int n = 0; n < 4; ++n)
#pragma unroll
              for (int m = 0; m < 4; ++m)
                acc[m][n] = __builtin_amdgcn_mfma_f32_16x16x32_bf16(A[c & 1][m], wreg[c - 2][n], acc[m][n], 0, 0, 0);
          }
          if (c + 2 < 8) ISSUE(c & 1, KSEL1(c + 2));
        }
      } else {
        ISSUE(0, KSEL0(0));
        ISSUE(1, KSEL0(1));
#pragma unroll
        for (int c = 0; c < 4; ++c) {
          if (c < 3) VMWAIT4; else VMWAIT0;
          if (c < 2) {
            const int kk = 64 * q + 32 * c;
#pragma unroll
            for (int n = 0; n < 4; ++n) {
              const int byteoff = (((n * 16 + l15) * KL + kk + 8 * lhi) * 2) ^ ((l15 & 7) << 4);
              short8 bb = *(const short8*)((const char*)WuL + byteoff);
#pragma unroll
              for (int m = 0; m < 4; ++m)
                acc[m][n] = __builtin_amdgcn_mfma_f32_16x16x32_bf16(A[c & 1][m], bb, acc[m][n], 0, 0, 0);
            }
          } else {
#pragma unroll
            for (int n = 0; n < 4; ++n)
#pragma unroll
              for (int m = 0; m < 4; ++m)
                acc[m][n] = __builtin_amdgcn_mfma_f32_16x16x32_bf16(A[c & 1][m], wreg[c - 2][n], acc[m][n], 0, 0, 0);
          }
          if (c + 2 < 4) ISSUE(c & 1, KSEL0(c + 2));
        }
      }
#undef ISSUE
#undef KSEL1
#undef KSEL0

      // 2-round reduce: waves 0-3 write tiles 0-3 (no pre-sync needed: prev wave's
      // end-sync separates red reuse), sync, waves 4-7 add, sync.
      {
        float* tile = red[q & 3];
        if (q < 4) {
#pragma unroll
          for (int m = 0; m < 4; ++m)
#pragma unroll
            for (int n = 0; n < 4; ++n)
              *(f32x4*)&tile[(n * 16 + l15) * RSTR + m * 16 + lhi * 4] = acc[m][n];
        }
        __syncthreads();
        if (q >= 4) {
#pragma unroll
          for (int m = 0; m < 4; ++m)
#pragma unroll
            for (int n = 0; n < 4; ++n) {
              float* p = &tile[(n * 16 + l15) * RSTR + m * 16 + lhi * 4];
              f32x4 v = *(f32x4*)p; v += acc[m][n]; *(f32x4*)p = v;
            }
        }
        __syncthreads();
      }

      // fused LSTM cell (2 adjacent hidden units per thread), sum 4 tiles
      {
        const int u = tid * 2;
        const int b = u >> 4, jj = u & 15;  // jj even
        const int C = jt * 16 + jj;         // global col, even
        unsigned short hyv[2];
#pragma unroll
        for (int e = 0; e < 2; ++e) {
          const int j2 = jj + e;
          float ig = 0.f, fg = 0.f, gg = 0.f, og = 0.f;
#pragma unroll
          for (int t = 0; t < 4; ++t) {
            ig += red[t][(0 * 16 + j2) * RSTR + b];
            fg += red[t][(1 * 16 + j2) * RSTR + b];
            gg += red[t][(2 * 16 + j2) * RSTR + b];
            og += red[t][(3 * 16 + j2) * RSTR + b];
          }
          const float i_ = sigmoidf_(ig);
          const float f_ = sigmoidf_(fg);
          const float g_ = tanhf_(gg);
          const float o_ = sigmoidf_(og);
          const float cv = f_ * cS[b * 16 + j2] + i_ * g_;
          cS[b * 16 + j2] = cv;
          hyv[e] = f2bf(o_ * tanhf_(cv));
        }
        const unsigned packed = (unsigned)hyv[0] | ((unsigned)hyv[1] << 16);
        st_h4(HSL(lyr, w + 1) + TOFF(b, C), packed);
      }
    }

    // ---- drain + post flag row w+1 (every wave, active or idle) ----
    asm volatile("s_waitcnt vmcnt(0)" ::: "memory");
    __syncthreads();
    if (tid == 0)
      __hip_atomic_store(FROW(w + 1) + lyr * 64 + jt, 1u,
                         __ATOMIC_RELAXED, __HIP_MEMORY_SCOPE_AGENT);
  }
#undef HSL
#undef TOFF
#undef FROW
}

// ---------------- batched output projection: out[t] = h3[t] @ L^T ----------------
// h3 history = layer-3 monotonic slab (TILED layout), position t at slab index t.
// M = 8192 (= 128 positions x 64 rows), N = 512, K = 1024. mt = position index.
__global__ __launch_bounds__(256) void proj_kernel(
    const unsigned short* __restrict__ hist, const float* __restrict__ Lm,
    float* __restrict__ out) {
  __shared__ __align__(16) unsigned short As[64 * 136];
  const int tid = threadIdx.x;
  const int q = tid >> 6;
  const int lane = tid & 63;
  const int l15 = lane & 15;
  const int lhi = lane >> 4;
  const int mt = blockIdx.x >> 3;   // position (time) index 0..127
  const int nt = blockIdx.x & 7;

  f32x4 acc[4];
#pragma unroll
  for (int m = 0; m < 4; ++m) acc[m] = (f32x4){0.f, 0.f, 0.f, 0.f};

  for (int kb = 0; kb < 8; ++kb) {
    __syncthreads();
#pragma unroll
    for (int i = 0; i < 4; ++i) {
      int g = tid + 256 * i;
      int row = g >> 4, cu = g & 15;
      const int C = kb * 128 + cu * 8;   // global k-col of the 8-elem chunk
      *(short8*)(&As[row * 136 + cu * 8]) =
          *(const short8*)(&hist[(size_t)mt * 65536 + (size_t)(C >> 5) * 2048
                                 + (size_t)row * 32 + (C & 31)]);
    }
    __syncthreads();
#pragma unroll
    for (int kk = 0; kk < 4; ++kk) {
      const int ko = kk * 32 + 8 * lhi;
      const float* src = Lm + ((size_t)nt * 64 + q * 16 + l15) * H + kb * 128 + ko;
      short8 bb = pack8(*(const float4*)src, *(const float4*)(src + 4));
#pragma unroll
      for (int m = 0; m < 4; ++m) {
        short8 a = *(const short8*)(&As[(m * 16 + l15) * 136 + ko]);
        acc[m] = __builtin_amdgcn_mfma_f32_16x16x32_bf16(a, bb, acc[m], 0, 0, 0);
      }
    }
  }
  const int col = nt * 64 + q * 16 + l15;
#pragma unroll
  for (int m = 0; m < 4; ++m)
#pragma unroll
    for (int j = 0; j < 4; ++j) {
      const int row = mt * 64 + m * 16 + lhi * 4 + j;
      out[(size_t)row * NOUTD + col] = acc[m][j];
    }
}

extern "C" void kernel_launch(void* const* d_in, const int* in_sizes, int n_in,
                              void* d_out, int out_size, void* d_ws, size_t ws_size,
                              hipStream_t stream) {
  const float* hx = (const float*)d_in[0];
  const float* cx = (const float*)d_in[1];
  const float* Wm = (const float*)d_in[2];
  const float* Um = (const float*)d_in[3];
  const float* Lm = (const float*)d_in[4];
  float* out = (float*)d_out;

  char* ws = (char*)d_ws;
  unsigned* flags = (unsigned*)ws;                              // 256 KB flag rows
  unsigned short* hmon = (unsigned short*)(ws + (1 << 18));     // 64 MiB monotonic h slabs

  hipMemsetAsync(flags, 0, 262144, stream);

  void* args[] = {(void*)&hx, (void*)&cx, (void*)&Wm, (void*)&Um,
                  (void*)&hmon, (void*)&flags};
  hipLaunchCooperativeKernel((const void*)lstm_persist, dim3(256), dim3(512),
                             args, 0, stream);
  // layer-3 slab base: position t+3 lives at slab index t => history row-block t
  const unsigned short* hist = hmon + (size_t)3 * 128 * BH;
  proj_kernel<<<dim3(1024), dim3(256), 0, stream>>>(hist, Lm, out);
}